// Round 1
// baseline (15148.717 us; speedup 1.0000x reference)
//
#include <hip/hip_runtime.h>
#include <hip/hip_bf16.h>

// Problem constants (B,S,D)=(2,2048,4096), H=32, KVH=8, HD=128, N_REP=4
constexpr int Bx = 2, Sx = 2048, Dx = 4096;
constexpr int NH = 32, NKVH = 8, HDIM = 128;
constexpr float SCALE = 0.08838834764831845f; // 1/sqrt(128)

// ---------------- fp32 tiled GEMM: C[M,N] = A[M,K] @ B[K,N] ----------------
// 128x128 tile, BK=16, 256 threads, 8x8 microtile. M,N,K multiples of 128/16.
__global__ __launch_bounds__(256)
void gemm_f32(const float* __restrict__ A, const float* __restrict__ B,
              float* __restrict__ C, int M, int N, int K) {
    __shared__ float As[16][132];   // A tile stored transposed [k][m]
    __shared__ float Bs[16][132];   // B tile [k][n]
    const int tid = threadIdx.x;
    const int tx = tid & 15, ty = tid >> 4;
    const int bm = blockIdx.y * 128, bn = blockIdx.x * 128;

    float acc[8][8] = {};
    const float* Ab = A + (size_t)bm * K;
    const float* Bb = B + bn;

    for (int k0 = 0; k0 < K; k0 += 16) {
        // A tile: 128 rows x 16 cols = 512 float4, 2 per thread
#pragma unroll
        for (int i = 0; i < 2; ++i) {
            int idx = tid * 2 + i;
            int r = idx >> 2, c4 = (idx & 3) * 4;
            float4 va = *reinterpret_cast<const float4*>(Ab + (size_t)r * K + k0 + c4);
            As[c4 + 0][r] = va.x; As[c4 + 1][r] = va.y;
            As[c4 + 2][r] = va.z; As[c4 + 3][r] = va.w;
        }
        // B tile: 16 rows x 128 cols = 512 float4, 2 per thread
#pragma unroll
        for (int i = 0; i < 2; ++i) {
            int idx = tid + i * 256;
            int r = idx >> 5, c4 = (idx & 31) * 4;
            float4 vb = *reinterpret_cast<const float4*>(Bb + (size_t)(k0 + r) * N + c4);
            *reinterpret_cast<float4*>(&Bs[r][c4]) = vb;
        }
        __syncthreads();
#pragma unroll
        for (int kk = 0; kk < 16; ++kk) {
            float a[8], b[8];
#pragma unroll
            for (int i = 0; i < 8; ++i) a[i] = As[kk][ty * 8 + i];
#pragma unroll
            for (int j = 0; j < 8; ++j) b[j] = Bs[kk][tx * 8 + j];
#pragma unroll
            for (int i = 0; i < 8; ++i)
#pragma unroll
                for (int j = 0; j < 8; ++j)
                    acc[i][j] += a[i] * b[j];
        }
        __syncthreads();
    }
    float* Cb = C + (size_t)(bm + ty * 8) * N + bn + tx * 8;
#pragma unroll
    for (int i = 0; i < 8; ++i)
#pragma unroll
        for (int j = 0; j < 8; ++j)
            Cb[(size_t)i * N + j] = acc[i][j];
}

// ---------------- RoPE (interleaved pairs), in-place ----------------
// t layout: (B, S, nh, HDIM) contiguous; pair p -> elements 2p, 2p+1.
__global__ void rope_k(float* __restrict__ t, const float* __restrict__ cosb,
                       const float* __restrict__ sinb, int nh, int total_pairs) {
    int p = blockIdx.x * blockDim.x + threadIdx.x;
    if (p >= total_pairs) return;
    int d2 = p & 63;
    int s = (p / (nh * 64)) % Sx;
    float c = cosb[s * 64 + d2], sn = sinb[s * 64 + d2];
    float t1 = t[2 * p], t2 = t[2 * p + 1];
    t[2 * p]     = t1 * c - t2 * sn;
    t[2 * p + 1] = t1 * sn + t2 * c;
}

// ---------------- causal GQA attention, one block per (b,h,q_row) ----------
// Reads q row, writes output row IN-PLACE into q (1:1 mapping, safe).
__global__ __launch_bounds__(256)
void attn_k(float* __restrict__ q, const float* __restrict__ k,
            const float* __restrict__ v) {
    __shared__ float sc[Sx];      // scores/probs, 8 KB
    __shared__ float qs[HDIM];
    __shared__ float red[256];
    const int qi = blockIdx.x, h = blockIdx.y, b = blockIdx.z;
    const int tid = threadIdx.x;
    const int kvh = h >> 2;       // N_REP = 4
    const size_t qoff = (((size_t)b * Sx + qi) * NH + h) * HDIM;

    if (tid < HDIM) qs[tid] = q[qoff + tid] * SCALE;
    __syncthreads();

    const int nk = qi + 1;        // causal: keys 0..qi
    const int wave = tid >> 6, lane = tid & 63;
    const float* kb = k + ((size_t)b * Sx * NKVH + kvh) * HDIM;

    for (int kk = wave; kk < nk; kk += 4) {
        const float* kr = kb + (size_t)kk * NKVH * HDIM;
        float p = qs[lane] * kr[lane] + qs[lane + 64] * kr[lane + 64];
#pragma unroll
        for (int m = 32; m >= 1; m >>= 1) p += __shfl_xor(p, m);
        if (lane == 0) sc[kk] = p;
    }
    __syncthreads();

    // softmax over sc[0..nk)
    float mx = -1e30f;
    for (int i = tid; i < nk; i += 256) mx = fmaxf(mx, sc[i]);
    red[tid] = mx; __syncthreads();
    for (int s2 = 128; s2 > 0; s2 >>= 1) {
        if (tid < s2) red[tid] = fmaxf(red[tid], red[tid + s2]);
        __syncthreads();
    }
    mx = red[0]; __syncthreads();

    float sum = 0.f;
    for (int i = tid; i < nk; i += 256) {
        float e = __expf(sc[i] - mx);
        sc[i] = e; sum += e;
    }
    red[tid] = sum; __syncthreads();
    for (int s2 = 128; s2 > 0; s2 >>= 1) {
        if (tid < s2) red[tid] += red[tid + s2];
        __syncthreads();
    }
    const float inv = 1.0f / red[0];
    __syncthreads();   // protect red[0] before reuse below

    // PV: thread = (half, d); coalesced V row reads
    const int d = tid & 127, half = tid >> 7;
    const float* vb = v + ((size_t)b * Sx * NKVH + kvh) * HDIM + d;
    float acc = 0.f;
    for (int kk = half; kk < nk; kk += 2)
        acc += sc[kk] * vb[(size_t)kk * NKVH * HDIM];
    red[tid] = acc; __syncthreads();
    if (tid < 128) q[qoff + tid] = (red[tid] + red[tid + 128]) * inv;
}

// ---------------- launch ----------------
extern "C" void kernel_launch(void* const* d_in, const int* in_sizes, int n_in,
                              void* d_out, int out_size, void* d_ws, size_t ws_size,
                              hipStream_t stream) {
    const float* x    = (const float*)d_in[0];
    const float* wq   = (const float*)d_in[1];
    const float* wk   = (const float*)d_in[2];
    const float* wv   = (const float*)d_in[3];
    const float* wo   = (const float*)d_in[4];
    const float* cosb = (const float*)d_in[5];
    const float* sinb = (const float*)d_in[6];
    // d_in[7] = mask (pure causal, recomputed on the fly), d_in[8] = start_pos (==0, unused by ref)
    float* out = (float*)d_out;

    float* q    = (float*)d_ws;                         // B*S*NH*HD   = 16.8M f
    float* kbuf = q    + (size_t)Bx * Sx * NH   * HDIM; // B*S*KVH*HD  =  4.2M f
    float* vbuf = kbuf + (size_t)Bx * Sx * NKVH * HDIM; //             =  4.2M f

    const int M = Bx * Sx;          // 4096
    dim3 blk(256);

    gemm_f32<<<dim3(Dx / 128, M / 128), blk, 0, stream>>>(x, wq, q,    M, NH * HDIM,   Dx);
    gemm_f32<<<dim3((NKVH * HDIM) / 128, M / 128), blk, 0, stream>>>(x, wk, kbuf, M, NKVH * HDIM, Dx);
    gemm_f32<<<dim3((NKVH * HDIM) / 128, M / 128), blk, 0, stream>>>(x, wv, vbuf, M, NKVH * HDIM, Dx);

    const int qp = Bx * Sx * NH * 64, kp = Bx * Sx * NKVH * 64;
    rope_k<<<(qp + 255) / 256, blk, 0, stream>>>(q,    cosb, sinb, NH,   qp);
    rope_k<<<(kp + 255) / 256, blk, 0, stream>>>(kbuf, cosb, sinb, NKVH, kp);

    attn_k<<<dim3(Sx, NH, Bx), blk, 0, stream>>>(q, kbuf, vbuf);

    gemm_f32<<<dim3(Dx / 128, M / 128), blk, 0, stream>>>(q, wo, out, M, Dx, NH * HDIM);
}

// Round 2
// 5450.631 us; speedup vs baseline: 2.7793x; 2.7793x over previous
//
#include <hip/hip_runtime.h>
#include <hip/hip_bf16.h>

constexpr int Bx = 2, Sx = 2048, Dx = 4096;
constexpr int NH = 32, NKVH = 8, HDIM = 128;
constexpr float SCALE = 0.08838834764831845f; // 1/sqrt(128)

typedef unsigned short u16;
typedef __bf16 bf16x8 __attribute__((ext_vector_type(8)));
typedef float f32x4 __attribute__((ext_vector_type(4)));

__device__ __forceinline__ u16 f2bf(float f) {
    union { float f; unsigned int u; } v; v.f = f;
    unsigned int r = v.u + 0x7FFF + ((v.u >> 16) & 1);   // RNE
    return (u16)(r >> 16);
}

// ---------------- fp32 tiled GEMM: C[M,N] = A[M,K] @ B[K,N] ----------------
__global__ __launch_bounds__(256)
void gemm_f32(const float* __restrict__ A, const float* __restrict__ B,
              float* __restrict__ C, int M, int N, int K) {
    __shared__ float As[16][132];
    __shared__ float Bs[16][132];
    const int tid = threadIdx.x;
    const int tx = tid & 15, ty = tid >> 4;
    const int bm = blockIdx.y * 128, bn = blockIdx.x * 128;

    float acc[8][8] = {};
    const float* Ab = A + (size_t)bm * K;
    const float* Bb = B + bn;

    for (int k0 = 0; k0 < K; k0 += 16) {
#pragma unroll
        for (int i = 0; i < 2; ++i) {
            int idx = tid * 2 + i;
            int r = idx >> 2, c4 = (idx & 3) * 4;
            float4 va = *reinterpret_cast<const float4*>(Ab + (size_t)r * K + k0 + c4);
            As[c4 + 0][r] = va.x; As[c4 + 1][r] = va.y;
            As[c4 + 2][r] = va.z; As[c4 + 3][r] = va.w;
        }
#pragma unroll
        for (int i = 0; i < 2; ++i) {
            int idx = tid + i * 256;
            int r = idx >> 5, c4 = (idx & 31) * 4;
            float4 vb = *reinterpret_cast<const float4*>(Bb + (size_t)(k0 + r) * N + c4);
            *reinterpret_cast<float4*>(&Bs[r][c4]) = vb;
        }
        __syncthreads();
#pragma unroll
        for (int kk = 0; kk < 16; ++kk) {
            float a[8], b[8];
#pragma unroll
            for (int i = 0; i < 8; ++i) a[i] = As[kk][ty * 8 + i];
#pragma unroll
            for (int j = 0; j < 8; ++j) b[j] = Bs[kk][tx * 8 + j];
#pragma unroll
            for (int i = 0; i < 8; ++i)
#pragma unroll
                for (int j = 0; j < 8; ++j)
                    acc[i][j] += a[i] * b[j];
        }
        __syncthreads();
    }
    float* Cb = C + (size_t)(bm + ty * 8) * N + bn + tx * 8;
#pragma unroll
    for (int i = 0; i < 8; ++i)
#pragma unroll
        for (int j = 0; j < 8; ++j)
            Cb[(size_t)i * N + j] = acc[i][j];
}

// ------------- RoPE + scale + bf16 + (b,s,h,d)->(b,h,s,d) pack -------------
__global__ void pack_q(const float* __restrict__ q, const float* __restrict__ cosb,
                       const float* __restrict__ sinb, u16* __restrict__ qb) {
    int p = blockIdx.x * blockDim.x + threadIdx.x;   // pair index
    int d2 = p & 63;
    int rest = p >> 6;
    int h = rest & 31;
    int s = (rest >> 5) & (Sx - 1);
    int b = rest >> 16;
    float c = cosb[s * 64 + d2], sn = sinb[s * 64 + d2];
    float t1 = q[2 * (size_t)p], t2 = q[2 * (size_t)p + 1];
    size_t o = (((size_t)(b * NH + h)) * Sx + s) * HDIM + 2 * d2;
    qb[o]     = f2bf((t1 * c - t2 * sn) * SCALE);
    qb[o + 1] = f2bf((t1 * sn + t2 * c) * SCALE);
}

__global__ void pack_k(const float* __restrict__ k, const float* __restrict__ cosb,
                       const float* __restrict__ sinb, u16* __restrict__ kb) {
    int p = blockIdx.x * blockDim.x + threadIdx.x;
    int d2 = p & 63;
    int rest = p >> 6;
    int kvh = rest & 7;
    int s = (rest >> 3) & (Sx - 1);
    int b = rest >> 14;
    float c = cosb[s * 64 + d2], sn = sinb[s * 64 + d2];
    float t1 = k[2 * (size_t)p], t2 = k[2 * (size_t)p + 1];
    size_t o = (((size_t)(b * NKVH + kvh)) * Sx + s) * HDIM + 2 * d2;
    kb[o]     = f2bf(t1 * c - t2 * sn);
    kb[o + 1] = f2bf(t1 * sn + t2 * c);
}

// ------------- V transpose: (b,s,kvh,d) -> (b,kvh,d,s), bf16 -------------
__global__ void pack_v(const float* __restrict__ v, u16* __restrict__ vt) {
    int o = blockIdx.x * blockDim.x + threadIdx.x;   // output element index
    int s = o & (Sx - 1);
    int rest = o >> 11;
    int d = rest & 127;
    int rest2 = rest >> 7;
    int kvh = rest2 & 7;
    int b = rest2 >> 3;
    vt[(size_t)o] = f2bf(v[(((size_t)(b * Sx + s)) * NKVH + kvh) * HDIM + d]);
}

// ---------------- flash attention, bf16 MFMA 16x16x32 ----------------
// Block: 4 waves, 64 q rows (wave w owns rows q0..q0+15). Causal, GQA 4:1.
__global__ __launch_bounds__(256)
void fattn(const u16* __restrict__ qb, const u16* __restrict__ kb,
           const u16* __restrict__ vt, float* __restrict__ ao) {
    __shared__ __align__(16) u16 pls[4][16][72];   // P stage, pad->2-way (free)
    const int qt = blockIdx.x, h = blockIdx.y, b = blockIdx.z;
    const int kvh = h >> 2;
    const int tid = threadIdx.x;
    const int w = tid >> 6, lane = tid & 63;
    const int lg = lane >> 4, lr = lane & 15;
    const int q0 = qt * 64 + w * 16;

    // Q fragments (scale pre-folded): lane reads row lr, d = c*32 + lg*8 .. +8
    const u16* Qp = qb + (((size_t)(b * NH + h)) * Sx + q0) * HDIM;
    bf16x8 qf[4];
#pragma unroll
    for (int c = 0; c < 4; ++c)
        qf[c] = *reinterpret_cast<const bf16x8*>(Qp + (size_t)lr * HDIM + c * 32 + lg * 8);

    const u16* Kp = kb + ((size_t)(b * NKVH + kvh)) * Sx * HDIM;
    const u16* Vp = vt + ((size_t)(b * NKVH + kvh)) * (size_t)HDIM * Sx;

    float m_r[4], l_r[4];
    f32x4 oacc[8];
#pragma unroll
    for (int r = 0; r < 4; ++r) { m_r[r] = -INFINITY; l_r[r] = 0.f; }
#pragma unroll
    for (int n = 0; n < 8; ++n) oacc[n] = (f32x4){0.f, 0.f, 0.f, 0.f};

    for (int kt = 0; kt <= qt; ++kt) {
        // ---- S = Q K^T : 4 subtiles of 16 keys ----
        f32x4 sacc[4];
#pragma unroll
        for (int ks = 0; ks < 4; ++ks) {
            f32x4 a = (f32x4){0.f, 0.f, 0.f, 0.f};
            const u16* Kr = Kp + (size_t)(kt * 64 + ks * 16 + lr) * HDIM + lg * 8;
#pragma unroll
            for (int c = 0; c < 4; ++c) {
                bf16x8 kf = *reinterpret_cast<const bf16x8*>(Kr + c * 32);
                a = __builtin_amdgcn_mfma_f32_16x16x32_bf16(qf[c], kf, a, 0, 0, 0);
            }
            sacc[ks] = a;
        }
        // ---- causal mask (diagonal tile only) ----
        if (kt == qt) {
#pragma unroll
            for (int ks = 0; ks < 4; ++ks) {
                int col = qt * 64 + ks * 16 + lr;
#pragma unroll
                for (int r = 0; r < 4; ++r) {
                    int row = q0 + lg * 4 + r;
                    if (col > row) sacc[ks][r] = -1e30f;
                }
            }
        }
        // ---- online softmax (row = lg*4 + r, 16 lanes/group hold 16 cols) ----
        float mnew[4], alpha[4];
#pragma unroll
        for (int r = 0; r < 4; ++r) {
            float mx = fmaxf(fmaxf(sacc[0][r], sacc[1][r]), fmaxf(sacc[2][r], sacc[3][r]));
#pragma unroll
            for (int msk = 1; msk < 16; msk <<= 1) mx = fmaxf(mx, __shfl_xor(mx, msk));
            mnew[r] = fmaxf(m_r[r], mx);
            alpha[r] = __expf(m_r[r] - mnew[r]);
        }
        float psum[4] = {0.f, 0.f, 0.f, 0.f};
#pragma unroll
        for (int ks = 0; ks < 4; ++ks)
#pragma unroll
            for (int r = 0; r < 4; ++r) {
                float p = __expf(sacc[ks][r] - mnew[r]);
                sacc[ks][r] = p;
                psum[r] += p;
            }
#pragma unroll
        for (int r = 0; r < 4; ++r) {
#pragma unroll
            for (int msk = 1; msk < 16; msk <<= 1) psum[r] += __shfl_xor(psum[r], msk);
            l_r[r] = l_r[r] * alpha[r] + psum[r];
            m_r[r] = mnew[r];
        }
#pragma unroll
        for (int n = 0; n < 8; ++n)
#pragma unroll
            for (int r = 0; r < 4; ++r) oacc[n][r] *= alpha[r];
        // ---- stage P (D-layout -> LDS row-major) ----
#pragma unroll
        for (int ks = 0; ks < 4; ++ks)
#pragma unroll
            for (int r = 0; r < 4; ++r)
                pls[w][lg * 4 + r][ks * 16 + lr] = f2bf(sacc[ks][r]);
        __syncthreads();   // uniform trip count; fences LDS write->read
        // ---- PV: O += P @ V ----
#pragma unroll
        for (int ck = 0; ck < 2; ++ck) {
            bf16x8 pa = *reinterpret_cast<const bf16x8*>(&pls[w][lr][ck * 32 + lg * 8]);
            const size_t kbase = (size_t)(kt * 64 + ck * 32 + lg * 8);
#pragma unroll
            for (int n = 0; n < 8; ++n) {
                bf16x8 vf = *reinterpret_cast<const bf16x8*>(Vp + (size_t)(n * 16 + lr) * Sx + kbase);
                oacc[n] = __builtin_amdgcn_mfma_f32_16x16x32_bf16(pa, vf, oacc[n], 0, 0, 0);
            }
        }
    }
    // ---- epilogue: normalize, write fp32 (b, s, h*hd) ----
    float invl[4];
#pragma unroll
    for (int r = 0; r < 4; ++r) invl[r] = 1.0f / l_r[r];
    float* Ao = ao + ((size_t)(b * Sx) + q0) * (NH * HDIM) + h * HDIM;
#pragma unroll
    for (int n = 0; n < 8; ++n)
#pragma unroll
        for (int r = 0; r < 4; ++r)
            Ao[(size_t)(lg * 4 + r) * (NH * HDIM) + n * 16 + lr] = oacc[n][r] * invl[r];
}

// ---------------- launch ----------------
extern "C" void kernel_launch(void* const* d_in, const int* in_sizes, int n_in,
                              void* d_out, int out_size, void* d_ws, size_t ws_size,
                              hipStream_t stream) {
    const float* x    = (const float*)d_in[0];
    const float* wq   = (const float*)d_in[1];
    const float* wk   = (const float*)d_in[2];
    const float* wv   = (const float*)d_in[3];
    const float* wo   = (const float*)d_in[4];
    const float* cosb = (const float*)d_in[5];
    const float* sinb = (const float*)d_in[6];
    float* out = (float*)d_out;

    const size_t QN = (size_t)Bx * Sx * NH * HDIM;      // 16.78M
    const size_t KN = (size_t)Bx * Sx * NKVH * HDIM;    //  4.19M

    float* q   = (float*)d_ws;          // fp32 Q proj; later reused as attn out
    float* kf  = q + QN;
    float* vf  = kf + KN;
    u16*  qb   = (u16*)(vf + KN);       // bf16 packed Q (b,h,s,d)
    u16*  kb   = qb + QN;               // bf16 packed K (b,kvh,s,d)
    u16*  vt   = kb + KN;               // bf16 packed V^T (b,kvh,d,s)
    float* ao  = q;                     // attention out aliases q (safe: stream order)

    const int M = Bx * Sx;              // 4096
    dim3 blk(256);

    gemm_f32<<<dim3(Dx / 128, M / 128), blk, 0, stream>>>(x, wq, q,  M, NH * HDIM,   Dx);
    gemm_f32<<<dim3((NKVH * HDIM) / 128, M / 128), blk, 0, stream>>>(x, wk, kf, M, NKVH * HDIM, Dx);
    gemm_f32<<<dim3((NKVH * HDIM) / 128, M / 128), blk, 0, stream>>>(x, wv, vf, M, NKVH * HDIM, Dx);

    pack_q<<<(int)(QN / 2 / 256), blk, 0, stream>>>(q,  cosb, sinb, qb);
    pack_k<<<(int)(KN / 2 / 256), blk, 0, stream>>>(kf, cosb, sinb, kb);
    pack_v<<<(int)(KN / 256),     blk, 0, stream>>>(vf, vt);

    fattn<<<dim3(Sx / 64, NH, Bx), blk, 0, stream>>>(qb, kb, vt, ao);

    gemm_f32<<<dim3(Dx / 128, M / 128), blk, 0, stream>>>(ao, wo, out, M, Dx, NH * HDIM);
}